// Round 4
// baseline (244.540 us; speedup 1.0000x reference)
//
#include <hip/hip_runtime.h>

// LightweightConv: x (T,B,C) fp32, weight (H,1,K) fp32 shared across R=C/H channels.
// out[t,b,c] = sum_k w[h(c),k] * x[t-15+k, b, c]   (cross-correlation, pad 15/15)
//
// r4: read-volume-bound model. CH=32 two-step register sliding window cuts
// L1-level read amplification from 2.875x (CH=16) to 1.94x.

#define T_DIM 4096
#define B_DIM 8
#define C_DIM 1024
#define H_DIM 16
#define K_DIM 31
#define PAD   15
#define COLS  (B_DIM * C_DIM / 4)   // 2048 float4-columns; stride between t-rows
#define CH    32                    // t-outputs per thread (two 16-row steps)
#define WIN   (K_DIM - 1 + CH)      // 62 float4 window positions

__global__ __launch_bounds__(256, 2)
void lconv_kernel(const float* __restrict__ x,
                  const float* __restrict__ w,
                  float* __restrict__ out) {
    __shared__ float lw[H_DIM * K_DIM];   // 496 floats
    const int tid = threadIdx.x;
    for (int i = tid; i < H_DIM * K_DIM; i += 256) lw[i] = w[i];
    __syncthreads();

    const int col = blockIdx.x * 256 + tid;     // float4 column, 0..2047 (= b*256 + c/4)
    const int h   = (col & 255) >> 4;           // head = (c % 1024) / 64; uniform per 16 lanes
    const int t0  = blockIdx.y * CH;

    const float4* xp = (const float4*)x + (long long)(t0 - PAD) * COLS + col;
    float4* op = (float4*)out + (long long)t0 * COLS + col;

    const bool interior = (t0 >= PAD) && (t0 + CH + PAD <= T_DIM);

    float4 win[WIN];   // static indices only -> registers

    float wk[K_DIM];
    #pragma unroll
    for (int k = 0; k < K_DIM; ++k) wk[k] = lw[h * K_DIM + k];

    // ---- Step 1: rows t0-15 .. t0+30 (win[0..45]) -> outputs j=0..15 ----
    if (interior) {
        #pragma unroll
        for (int i = 0; i < 46; ++i)
            win[i] = xp[(long long)i * COLS];
    } else {
        #pragma unroll
        for (int i = 0; i < 46; ++i) {
            const int t = t0 - PAD + i;
            win[i] = (t >= 0 && t < T_DIM) ? xp[(long long)i * COLS]
                                           : float4{0.f, 0.f, 0.f, 0.f};
        }
    }

    #pragma unroll
    for (int j = 0; j < 16; ++j) {
        float4 a = {0.f, 0.f, 0.f, 0.f};
        #pragma unroll
        for (int k = 0; k < K_DIM; ++k) {
            a.x = fmaf(wk[k], win[j + k].x, a.x);
            a.y = fmaf(wk[k], win[j + k].y, a.y);
            a.z = fmaf(wk[k], win[j + k].z, a.z);
            a.w = fmaf(wk[k], win[j + k].w, a.w);
        }
        op[(long long)j * COLS] = a;
    }

    // ---- Step 2: rows t0+31 .. t0+46 (win[46..61]) -> outputs j=16..31 ----
    if (interior) {
        #pragma unroll
        for (int i = 46; i < WIN; ++i)
            win[i] = xp[(long long)i * COLS];
    } else {
        #pragma unroll
        for (int i = 46; i < WIN; ++i) {
            const int t = t0 - PAD + i;
            win[i] = (t >= 0 && t < T_DIM) ? xp[(long long)i * COLS]
                                           : float4{0.f, 0.f, 0.f, 0.f};
        }
    }

    #pragma unroll
    for (int j = 16; j < CH; ++j) {
        float4 a = {0.f, 0.f, 0.f, 0.f};
        #pragma unroll
        for (int k = 0; k < K_DIM; ++k) {
            a.x = fmaf(wk[k], win[j + k].x, a.x);
            a.y = fmaf(wk[k], win[j + k].y, a.y);
            a.z = fmaf(wk[k], win[j + k].z, a.z);
            a.w = fmaf(wk[k], win[j + k].w, a.w);
        }
        op[(long long)j * COLS] = a;
    }
}

extern "C" void kernel_launch(void* const* d_in, const int* in_sizes, int n_in,
                              void* d_out, int out_size, void* d_ws, size_t ws_size,
                              hipStream_t stream) {
    const float* x = (const float*)d_in[0];   // (T, B, C)
    const float* w = (const float*)d_in[1];   // (H, 1, K)
    float* out = (float*)d_out;               // (T, B, C)

    dim3 grid(COLS / 256, T_DIM / CH);        // (8, 128) = 1024 blocks
    lconv_kernel<<<grid, 256, 0, stream>>>(x, w, out);
}